// Round 4
// baseline (310.175 us; speedup 1.0000x reference)
//
#include <hip/hip_runtime.h>
#include <math.h>

#define OS    320      // oversampled grid (ceil(1.25*256))
#define IMN   256
#define NCOIL 8
#define PI_F  3.14159265358979f
#define BETA_F 10.955108f   // pi*sqrt((4.8*0.75)^2 - 0.8)
#define GSCALE 65536.0f     // fp16 grid scaling

typedef _Float16 half8  __attribute__((ext_vector_type(8)));
typedef _Float16 half2v __attribute__((ext_vector_type(2)));

// ---- Kaiser-Bessel kernel: exact A&S I0 polynomial (matches reference) ----
__device__ __forceinline__ float i0f(float x) {
    if (x < 3.75f) {
        float y = x * (1.0f / 3.75f); y *= y;
        return 1.0f + y*(3.5156229f + y*(3.0899424f + y*(1.2067492f
             + y*(0.2659732f + y*(0.0360768f + y*0.0045813f)))));
    } else {
        float t = 3.75f / x;
        float p = 0.39894228f + t*(0.01328592f + t*(0.00225319f + t*(-0.00157565f
              + t*(0.00916281f + t*(-0.02057706f + t*(0.02635537f + t*(-0.01647633f
              + t*0.00392377f)))))));
        return expf(x) * rsqrtf(x) * p;
    }
}

__device__ __forceinline__ float kbf(float u) {
    float q = 1.0f - u * u;
    q = fmaxf(q, 0.0f);
    return i0f(BETA_F * sqrtf(q));
}

__device__ __forceinline__ float apod1(int i) {
    float idx = (float)(i - 128);
    float c = PI_F * 6.0f * idx * (1.0f / (float)OS);
    float a = sqrtf(BETA_F * BETA_F - c * c);
    float sh = 0.5f * (expf(a) - expf(-a));
    return a / sh;
}

// ---- K1: fused apod + pad + DFT along x.  Block = image row iy (0..255).
// Grid row y=(iy+192)%320; grid col n=(m+192)%320 <-> image col ix=m.
// Reads image directly (uniform addresses -> scalar/broadcast loads).
// out: [kx][y][coil] float2.
__global__ __launch_bounds__(320) void dft_pass1(const float* __restrict__ imr,
                                                 const float* __restrict__ imi,
                                                 float2* __restrict__ out) {
    __shared__ float aptab[IMN];
    int iy = blockIdx.x;              // image row
    int t  = threadIdx.x;             // kx
    if (t < IMN) aptab[t] = apod1(t);
    __syncthreads();

    float ar[8], ai[8];
    #pragma unroll
    for (int b = 0; b < 8; ++b) { ar[b] = 0.f; ai[b] = 0.f; }

    float ang_t = (float)t * (-2.0f * PI_F / (float)OS);
    float wsr = cosf(ang_t), wsi = sinf(ang_t);

    const float* pr  = imr + iy * IMN;   // coil stride IMN*IMN
    const float* pim = imi + iy * IMN;

    int idx = (t * 192) % 320;   // (t*n)%320 at m=0 (n=192)
    float wr = 1.f, wi = 0.f;
    #pragma unroll 4
    for (int m = 0; m < 256; ++m) {
        if (m == 128) idx = 0;               // n wraps 319 -> 0
        if ((m & 15) == 0) {                  // exact twiddle refresh
            float ang = (float)idx * (-2.0f * PI_F / (float)OS);
            wr = cosf(ang); wi = sinf(ang);
        }
        float ap = aptab[m];
        float awr = wr * ap, awi = wi * ap;
        #pragma unroll
        for (int b = 0; b < 8; ++b) {
            float xr = pr [b * (IMN * IMN) + m];
            float xi = pim[b * (IMN * IMN) + m];
            ar[b] = fmaf(xr, awr, fmaf(-xi, awi, ar[b]));
            ai[b] = fmaf(xr, awi, fmaf( xi, awr, ai[b]));
        }
        float nwr = fmaf(wr, wsr, -wi * wsi);
        float nwi = fmaf(wr, wsi,  wi * wsr);
        wr = nwr; wi = nwi;
        idx += t; if (idx >= OS) idx -= OS;
    }
    float ay = apod1(iy) * (1.0f / 256.0f);   // y-apod + /sqrt(ny*nx)
    int y = iy + 192; if (y >= OS) y -= OS;   // grid row
    float4* op = (float4*)(out + ((size_t)t * OS + y) * NCOIL);
    #pragma unroll
    for (int q = 0; q < 4; ++q)
        op[q] = make_float4(ar[2*q] * ay, ai[2*q] * ay,
                            ar[2*q+1] * ay, ai[2*q+1] * ay);
}

// ---- K2: DFT along y (no LDS; uniform global reads); fp16 grid out ----
// in: [kx][y][coil] float2 (only y=(m+192)%320 rows valid/written).
// out: fp16 [(t+160)%320][(kx+160)%320][coil]  (fftshift folded).
__global__ __launch_bounds__(320) void dft_pass2(const float2* __restrict__ in,
                                                 half2v* __restrict__ outg) {
    int kx = blockIdx.x;
    int t  = threadIdx.x;
    const float4* row = (const float4*)(in + (size_t)kx * OS * NCOIL);

    float ar[8], ai[8];
    #pragma unroll
    for (int b = 0; b < 8; ++b) { ar[b] = 0.f; ai[b] = 0.f; }

    float ang_t = (float)t * (-2.0f * PI_F / (float)OS);
    float wsr = cosf(ang_t), wsi = sinf(ang_t);

    int idx = (t * 192) % 320;
    float wr = 1.f, wi = 0.f;
    #pragma unroll 4
    for (int m = 0; m < 256; ++m) {
        if (m == 128) idx = 0;
        if ((m & 15) == 0) {
            float ang = (float)idx * (-2.0f * PI_F / (float)OS);
            wr = cosf(ang); wi = sinf(ang);
        }
        int n = m + 192; if (n >= OS) n -= OS;
        const float4* xp = row + n * 4;
        #pragma unroll
        for (int q = 0; q < 4; ++q) {
            float4 x = xp[q];                 // coils 2q, 2q+1 (uniform)
            ar[2*q]   = fmaf(x.x, wr, fmaf(-x.y, wi, ar[2*q]));
            ai[2*q]   = fmaf(x.x, wi, fmaf( x.y, wr, ai[2*q]));
            ar[2*q+1] = fmaf(x.z, wr, fmaf(-x.w, wi, ar[2*q+1]));
            ai[2*q+1] = fmaf(x.z, wi, fmaf( x.w, wr, ai[2*q+1]));
        }
        float nwr = fmaf(wr, wsr, -wi * wsi);
        float nwi = fmaf(wr, wsi,  wi * wsr);
        wr = nwr; wi = nwi;
        idx += t; if (idx >= OS) idx -= OS;
    }
    int r = t + 160;  if (r >= OS) r -= OS;   // fftshift fold (rows)
    int c = kx + 160; if (c >= OS) c -= OS;   // fftshift fold (cols)
    half8 h0, h1;
    #pragma unroll
    for (int q = 0; q < 4; ++q) {
        h0[2*q]   = (_Float16)(ar[q] * GSCALE);
        h0[2*q+1] = (_Float16)(ai[q] * GSCALE);
        h1[2*q]   = (_Float16)(ar[q+4] * GSCALE);
        h1[2*q+1] = (_Float16)(ai[q+4] * GSCALE);
    }
    half8* gp = (half8*)(outg + ((size_t)r * OS + c) * NCOIL);
    gp[0] = h0; gp[1] = h1;
}

// ---- K3: KB 6x6 gather; 8 coil-lanes per point; all 36 loads issued
// before the kbf weight computation (latency hidden under kbf/shfl). ----
__global__ __launch_bounds__(256) void interp_kernel(const float* __restrict__ trj,
                                                     const half2v* __restrict__ g,
                                                     float2* __restrict__ out, int K) {
    int tid = blockIdx.x * 256 + threadIdx.x;
    int k = tid >> 3;          // point index
    int c = tid & 7;           // coil index (lane role)
    if (k >= K) return;
    float ty = trj[2 * k + 0], tx = trj[2 * k + 1];
    float cy = ty * 1.25f + 160.0f;   // in [0, 320)
    float cx = tx * 1.25f + 160.0f;
    int y0 = (int)ceilf(cy - 3.0f);   // in [-3, 317]
    int x0 = (int)ceilf(cx - 3.0f);

    int rowoff[6], coloff[6];
    #pragma unroll
    for (int j = 0; j < 6; ++j) {
        int yy = y0 + j; if (yy < 0) yy += OS; if (yy >= OS) yy -= OS;
        rowoff[j] = yy * (OS * NCOIL);
        int xx = x0 + j; if (xx < 0) xx += OS; if (xx >= OS) xx -= OS;
        coloff[j] = xx * NCOIL + c;
    }

    // issue all 36 gathers (4B/lane; 8 lanes of a point = one 32B cell)
    half2v h[36];
    #pragma unroll
    for (int j = 0; j < 6; ++j)
        #pragma unroll
        for (int l = 0; l < 6; ++l)
            h[j * 6 + l] = g[rowoff[j] + coloff[l]];

    // 12 KB weights per point: 2 kbf evals per lane, distribute via shfl
    float argu = (c < 6) ? ((float)(y0 + c) - cy) * (1.0f / 3.0f)
                         : ((float)(x0 + (c - 6)) - cx) * (1.0f / 3.0f);
    float u = kbf(argu);
    float argv = ((float)(x0 + 2 + (c & 3)) - cx) * (1.0f / 3.0f);
    float v = kbf(argv);
    int lane = threadIdx.x & 63;
    int gb = lane & 56;               // 8-lane group base within wave
    float wy0 = __shfl(u, gb + 0), wy1 = __shfl(u, gb + 1), wy2 = __shfl(u, gb + 2);
    float wy3 = __shfl(u, gb + 3), wy4 = __shfl(u, gb + 4), wy5 = __shfl(u, gb + 5);
    float wx0 = __shfl(u, gb + 6), wx1 = __shfl(u, gb + 7);
    float wx2 = __shfl(v, gb + 0), wx3 = __shfl(v, gb + 1);
    float wx4 = __shfl(v, gb + 2), wx5 = __shfl(v, gb + 3);
    float wy[6] = {wy0, wy1, wy2, wy3, wy4, wy5};
    float wx[6] = {wx0, wx1, wx2, wx3, wx4, wx5};

    float accr = 0.f, acci = 0.f;
    #pragma unroll
    for (int j = 0; j < 6; ++j) {
        float wyj = wy[j];
        #pragma unroll
        for (int l = 0; l < 6; ++l) {
            float w = wyj * wx[l];
            half2v hv = h[j * 6 + l];
            accr = fmaf(w, (float)hv.x, accr);
            acci = fmaf(w, (float)hv.y, acci);
        }
    }
    const float s = 1.0f / (36.0f * GSCALE);
    out[(size_t)c * K + k] = make_float2(accr * s, acci * s);
}

extern "C" void kernel_launch(void* const* d_in, const int* in_sizes, int n_in,
                              void* d_out, int out_size, void* d_ws, size_t ws_size,
                              hipStream_t stream) {
    const float* imr = (const float*)d_in[0];
    const float* imi = (const float*)d_in[1];
    const float* trj = (const float*)d_in[2];
    int K = in_sizes[2] / 2;

    float2* buf1  = (float2*)d_ws;                       // [kx][y][coil] 6.55 MB
    half2v* gridh = (half2v*)(buf1 + (size_t)OS * OS * NCOIL);  // fp16 grid 3.28 MB

    (void)n_in; (void)out_size; (void)ws_size;

    dft_pass1<<<IMN, 320, 0, stream>>>(imr, imi, buf1);
    dft_pass2<<<OS, 320, 0, stream>>>(buf1, gridh);
    interp_kernel<<<(K * NCOIL + 255) / 256, 256, 0, stream>>>(trj, gridh,
                                                               (float2*)d_out, K);
}

// Round 5
// 200.782 us; speedup vs baseline: 1.5448x; 1.5448x over previous
//
#include <hip/hip_runtime.h>
#include <math.h>

#define OS    320      // oversampled grid (ceil(1.25*256))
#define IMN   256
#define NCOIL 8
#define PI_F  3.14159265358979f
#define BETA_F 10.955108f   // pi*sqrt((4.8*0.75)^2 - 0.8)
#define GSCALE 65536.0f     // fp16 grid scaling

typedef _Float16 half8  __attribute__((ext_vector_type(8)));
typedef _Float16 half4  __attribute__((ext_vector_type(4)));
typedef _Float16 half2v __attribute__((ext_vector_type(2)));

// ---- Kaiser-Bessel kernel: exact A&S I0 polynomial (matches reference) ----
__device__ __forceinline__ float i0f(float x) {
    if (x < 3.75f) {
        float y = x * (1.0f / 3.75f); y *= y;
        return 1.0f + y*(3.5156229f + y*(3.0899424f + y*(1.2067492f
             + y*(0.2659732f + y*(0.0360768f + y*0.0045813f)))));
    } else {
        float t = 3.75f / x;
        float p = 0.39894228f + t*(0.01328592f + t*(0.00225319f + t*(-0.00157565f
              + t*(0.00916281f + t*(-0.02057706f + t*(0.02635537f + t*(-0.01647633f
              + t*0.00392377f)))))));
        return expf(x) * rsqrtf(x) * p;
    }
}

__device__ __forceinline__ float kbf(float u) {
    float q = 1.0f - u * u;
    q = fmaxf(q, 0.0f);
    return i0f(BETA_F * sqrtf(q));
}

__device__ __forceinline__ float apod1(int i) {
    float idx = (float)(i - 128);
    float c = PI_F * 6.0f * idx * (1.0f / (float)OS);
    float a = sqrtf(BETA_F * BETA_F - c * c);
    float sh = 0.5f * (expf(a) - expf(-a));
    return a / sh;
}

// ---- K1: fused apod + pad + DFT along x.  Block = image row iy (0..255).
// Stage apodized image row in LDS (coalesced), then LDS-broadcast DFT loop.
// Grid col n=(m+192)%320 <-> image col m; grid row y=(iy+192)%320.
// out: [kx][y][coil] float2.
__global__ __launch_bounds__(320) void dft_pass1(const float* __restrict__ imr,
                                                 const float* __restrict__ imi,
                                                 float2* __restrict__ out) {
    __shared__ float2 xs[IMN * NCOIL];   // [m][coil], apodized; 16 KB
    int iy = blockIdx.x;
    int t  = threadIdx.x;                // kx
    if (t < IMN) {
        float ap = apod1(t);
        int base = iy * IMN + t;
        #pragma unroll
        for (int b = 0; b < 8; ++b) {
            float xr = imr[b * (IMN * IMN) + base];   // coalesced per coil
            float xi = imi[b * (IMN * IMN) + base];
            xs[t * 8 + b] = make_float2(xr * ap, xi * ap);
        }
    }
    __syncthreads();

    float ar[8], ai[8];
    #pragma unroll
    for (int b = 0; b < 8; ++b) { ar[b] = 0.f; ai[b] = 0.f; }
    float ang_t = (float)t * (-2.0f * PI_F / (float)OS);
    float wsr = cosf(ang_t), wsi = sinf(ang_t);
    int idx = (t * 192) % 320;            // (t*n) mod 320 at n=192
    float wr = 1.f, wi = 0.f;
    const float4* xv = (const float4*)xs;
    #pragma unroll 16
    for (int m = 0; m < 256; ++m) {
        if ((m & 15) == 0) {              // exact twiddle refresh
            float ang = (float)idx * (-2.0f * PI_F / (float)OS);
            wr = cosf(ang); wi = sinf(ang);
        }
        const float4* xp = xv + m * 4;
        #pragma unroll
        for (int q = 0; q < 4; ++q) {
            float4 x = xp[q];             // coils 2q, 2q+1 (LDS broadcast)
            ar[2*q]   = fmaf(x.x, wr, fmaf(-x.y, wi, ar[2*q]));
            ai[2*q]   = fmaf(x.x, wi, fmaf( x.y, wr, ai[2*q]));
            ar[2*q+1] = fmaf(x.z, wr, fmaf(-x.w, wi, ar[2*q+1]));
            ai[2*q+1] = fmaf(x.z, wi, fmaf( x.w, wr, ai[2*q+1]));
        }
        float nwr = fmaf(wr, wsr, -wi * wsi);
        float nwi = fmaf(wr, wsi,  wi * wsr);
        wr = nwr; wi = nwi;
        idx += t; if (idx >= OS) idx -= OS;
    }
    float ay = apod1(iy) * (1.0f / 256.0f);   // y-apod + /sqrt(ny*nx)
    int y = iy + 192; if (y >= OS) y -= OS;
    float4* op = (float4*)(out + ((size_t)t * OS + y) * NCOIL);
    #pragma unroll
    for (int q = 0; q < 4; ++q)
        op[q] = make_float4(ar[2*q] * ay, ai[2*q] * ay,
                            ar[2*q+1] * ay, ai[2*q+1] * ay);
}

// ---- K2: DFT along y (LDS-staged); write fp16 grid with fftshift folded ----
// in: [kx][y][coil] float2 (only y=(m+192)%320 rows valid).
// out: fp16 [(t+160)%320][(kx+160)%320][coil].
__global__ __launch_bounds__(320) void dft_pass2(const float2* __restrict__ in,
                                                 half2v* __restrict__ outg) {
    __shared__ float2 xs[IMN * NCOIL];
    int kx = blockIdx.x;
    int t  = threadIdx.x;
    const float2* row = in + (size_t)kx * OS * NCOIL;
    for (int i = t; i < IMN * NCOIL; i += 320) {
        int m = i >> 3, b = i & 7;
        int n = m + 192; if (n >= OS) n -= OS;
        xs[i] = row[n * NCOIL + b];
    }
    __syncthreads();

    float ar[8], ai[8];
    #pragma unroll
    for (int b = 0; b < 8; ++b) { ar[b] = 0.f; ai[b] = 0.f; }
    float ang_t = (float)t * (-2.0f * PI_F / (float)OS);
    float wsr = cosf(ang_t), wsi = sinf(ang_t);
    int idx = (t * 192) % 320;
    float wr = 1.f, wi = 0.f;
    const float4* xv = (const float4*)xs;
    #pragma unroll 16
    for (int m = 0; m < 256; ++m) {
        if ((m & 15) == 0) {
            float ang = (float)idx * (-2.0f * PI_F / (float)OS);
            wr = cosf(ang); wi = sinf(ang);
        }
        const float4* xp = xv + m * 4;
        #pragma unroll
        for (int q = 0; q < 4; ++q) {
            float4 x = xp[q];
            ar[2*q]   = fmaf(x.x, wr, fmaf(-x.y, wi, ar[2*q]));
            ai[2*q]   = fmaf(x.x, wi, fmaf( x.y, wr, ai[2*q]));
            ar[2*q+1] = fmaf(x.z, wr, fmaf(-x.w, wi, ar[2*q+1]));
            ai[2*q+1] = fmaf(x.z, wi, fmaf( x.w, wr, ai[2*q+1]));
        }
        float nwr = fmaf(wr, wsr, -wi * wsi);
        float nwi = fmaf(wr, wsi,  wi * wsr);
        wr = nwr; wi = nwi;
        idx += t; if (idx >= OS) idx -= OS;
    }
    int r = t + 160;  if (r >= OS) r -= OS;   // fftshift fold (rows)
    int c = kx + 160; if (c >= OS) c -= OS;   // fftshift fold (cols)
    half8 h0, h1;
    #pragma unroll
    for (int q = 0; q < 4; ++q) {
        h0[2*q]   = (_Float16)(ar[q] * GSCALE);
        h0[2*q+1] = (_Float16)(ai[q] * GSCALE);
        h1[2*q]   = (_Float16)(ar[q+4] * GSCALE);
        h1[2*q+1] = (_Float16)(ai[q+4] * GSCALE);
    }
    half8* gp = (half8*)(outg + ((size_t)r * OS + c) * NCOIL);
    gp[0] = h0; gp[1] = h1;
}

// ---- K3: KB 6x6 gather; 8 lanes per point = 4 coil-pairs x 2 tap-parities.
// Each 8B half4 load covers 2 coils of one tap; lanes 0-3 take even-l taps,
// lanes 4-7 odd-l taps -> 18 load instrs/point, x-pairs share 64B lines.
// All loads issued before kbf weight computation (latency hidden).
__global__ __launch_bounds__(256) void interp_kernel(const float* __restrict__ trj,
                                                     const half4* __restrict__ g4,
                                                     float2* __restrict__ out, int K) {
    int tid = blockIdx.x * 256 + threadIdx.x;
    int k = tid >> 3;          // point index
    int c = tid & 7;           // lane role
    int cp = c & 3;            // coil pair (coils 2cp, 2cp+1)
    int tp = c >> 2;           // tap parity (0: l=0,2,4; 1: l=1,3,5)
    if (k >= K) return;
    float ty = trj[2 * k + 0], tx = trj[2 * k + 1];
    float cy = ty * 1.25f + 160.0f;   // in [0, 320)
    float cx = tx * 1.25f + 160.0f;
    int y0 = (int)ceilf(cy - 3.0f);   // in [-3, 317]
    int x0 = (int)ceilf(cx - 3.0f);

    int rowoff[6], coloff[6];
    #pragma unroll
    for (int j = 0; j < 6; ++j) {
        int yy = y0 + j; if (yy < 0) yy += OS; if (yy >= OS) yy -= OS;
        rowoff[j] = yy * (OS * 4);    // half4 units: cell = 4 half4
        int xx = x0 + j; if (xx < 0) xx += OS; if (xx >= OS) xx -= OS;
        coloff[j] = xx * 4;
    }

    // issue all 18 paired-tap gathers
    half4 h[18];
    #pragma unroll
    for (int j = 0; j < 6; ++j)
        #pragma unroll
        for (int p = 0; p < 3; ++p)
            h[j * 3 + p] = g4[rowoff[j] + coloff[2 * p + tp] + cp];

    // 12 KB weights per point: 2 kbf evals per lane, distribute via shfl
    float argu = (c < 6) ? ((float)(y0 + c) - cy) * (1.0f / 3.0f)
                         : ((float)(x0 + (c - 6)) - cx) * (1.0f / 3.0f);
    float u = kbf(argu);
    float argv = ((float)(x0 + 2 + (c & 3)) - cx) * (1.0f / 3.0f);
    float v = kbf(argv);
    int lane = threadIdx.x & 63;
    int gb = lane & 56;               // 8-lane group base within wave
    float wy0 = __shfl(u, gb + 0), wy1 = __shfl(u, gb + 1), wy2 = __shfl(u, gb + 2);
    float wy3 = __shfl(u, gb + 3), wy4 = __shfl(u, gb + 4), wy5 = __shfl(u, gb + 5);
    float wx0 = __shfl(u, gb + 6), wx1 = __shfl(u, gb + 7);
    float wx2 = __shfl(v, gb + 0), wx3 = __shfl(v, gb + 1);
    float wx4 = __shfl(v, gb + 2), wx5 = __shfl(v, gb + 3);
    float wy[6] = {wy0, wy1, wy2, wy3, wy4, wy5};
    float wx[6] = {wx0, wx1, wx2, wx3, wx4, wx5};

    float accr0 = 0.f, acci0 = 0.f, accr1 = 0.f, acci1 = 0.f;
    #pragma unroll
    for (int j = 0; j < 6; ++j) {
        float wyj = wy[j];
        #pragma unroll
        for (int p = 0; p < 3; ++p) {
            float w = wyj * wx[2 * p + tp];
            half4 hv = h[j * 3 + p];
            accr0 = fmaf(w, (float)hv[0], accr0);
            acci0 = fmaf(w, (float)hv[1], acci0);
            accr1 = fmaf(w, (float)hv[2], accr1);
            acci1 = fmaf(w, (float)hv[3], acci1);
        }
    }
    // merge tap parities (lane c <-> c^4)
    accr0 += __shfl_xor(accr0, 4);
    acci0 += __shfl_xor(acci0, 4);
    accr1 += __shfl_xor(accr1, 4);
    acci1 += __shfl_xor(acci1, 4);

    const float s = 1.0f / (36.0f * GSCALE);
    float2 res = tp ? make_float2(accr1 * s, acci1 * s)
                    : make_float2(accr0 * s, acci0 * s);
    out[(size_t)(2 * cp + tp) * K + k] = res;   // coil 2cp+tp
}

extern "C" void kernel_launch(void* const* d_in, const int* in_sizes, int n_in,
                              void* d_out, int out_size, void* d_ws, size_t ws_size,
                              hipStream_t stream) {
    const float* imr = (const float*)d_in[0];
    const float* imi = (const float*)d_in[1];
    const float* trj = (const float*)d_in[2];
    int K = in_sizes[2] / 2;

    float2* buf1  = (float2*)d_ws;                       // [kx][y][coil] 6.55 MB
    half4*  gridh = (half4*)(buf1 + (size_t)OS * OS * NCOIL);  // fp16 grid 3.28 MB

    (void)n_in; (void)out_size; (void)ws_size;

    dft_pass1<<<IMN, 320, 0, stream>>>(imr, imi, buf1);
    dft_pass2<<<OS, 320, 0, stream>>>(buf1, (half2v*)gridh);
    interp_kernel<<<(K * NCOIL + 255) / 256, 256, 0, stream>>>(trj, gridh,
                                                               (float2*)d_out, K);
}